// Round 3
// baseline (362.530 us; speedup 1.0000x reference)
//
#include <hip/hip_runtime.h>

#define B_ 8
#define C_ 256
#define CI_ 128
#define N_ 4096
#define M_ 1024

typedef unsigned short u16;
typedef unsigned int u32;
typedef __bf16 bf16x8 __attribute__((ext_vector_type(8)));
typedef float f32x4 __attribute__((ext_vector_type(4)));
typedef u16 u16x4 __attribute__((ext_vector_type(4)));
typedef u16 u16x8 __attribute__((ext_vector_type(8)));

__device__ __forceinline__ float bf2f(u16 u) {
    u32 i = ((u32)u) << 16;
    float f;
    __builtin_memcpy(&f, &i, 4);
    return f;
}
__device__ __forceinline__ u16 f2bf(float f) {
    u32 i;
    __builtin_memcpy(&i, &f, 4);
    u32 r = (i + 0x7fffu + ((i >> 16) & 1u)) >> 16;
    return (u16)r;
}
// split v into bf16 hi + bf16 lo (v ~= hi+lo, rel err ~2^-18)
__device__ __forceinline__ void split_bf(float v, u16& hi, u16& lo) {
    hi = f2bf(v);
    lo = f2bf(v - bf2f(hi));
}
__device__ __forceinline__ bf16x8 ldb8(const u16* p) {
    return *reinterpret_cast<const bf16x8*>(p);
}
__device__ __forceinline__ f32x4 MFMA(bf16x8 a, bf16x8 b, f32x4 c) {
    return __builtin_amdgcn_mfma_f32_16x16x32_bf16(a, b, c, 0, 0, 0);
}

// ---------------- weight prep: fp32 -> split bf16, concat [theta;phi;g] ----------------
__global__ __launch_bounds__(256) void k_prep(
    const float* __restrict__ tw, const float* __restrict__ tb,
    const float* __restrict__ pw, const float* __restrict__ pb,
    const float* __restrict__ gw, const float* __restrict__ gb,
    const float* __restrict__ Ww,
    u16* __restrict__ Wcat_h, u16* __restrict__ Wcat_l,
    float* __restrict__ bcat, u16* __restrict__ Wwb) {
    int idx = blockIdx.x * 256 + threadIdx.x;
    if (idx < 384 * 256) {
        int r = idx >> 8, c = idx & 255;
        float v = (r < 128) ? tw[r * 256 + c]
                : (r < 256) ? pw[(r - 128) * 256 + c]
                            : gw[(r - 256) * 256 + c];
        u16 h, l;
        split_bf(v, h, l);
        Wcat_h[idx] = h;
        Wcat_l[idx] = l;
    } else if (idx < 384 * 256 + 256 * 128) {
        int k = idx - 384 * 256;
        Wwb[k] = f2bf(Ww[k]);
    } else if (idx < 384 * 256 + 256 * 128 + 384) {
        int r = idx - (384 * 256 + 256 * 128);
        bcat[r] = (r < 128) ? tb[r] : (r < 256) ? pb[r - 128] : gb[r - 256];
    }
}

// ---------------- x (B,C,N) fp32 -> x^T (B,N,C) split bf16 ----------------
__global__ __launch_bounds__(256) void k_tx(const float* __restrict__ x,
                                            u16* __restrict__ xbt_h, u16* __restrict__ xbt_l) {
    int bid = blockIdx.x;
    int b = bid >> 8, rem = bid & 255, nt = rem >> 2, ct = rem & 3;
    int n0 = nt * 64, c0 = ct * 64;
    __shared__ u16 th_[64][66];
    __shared__ u16 tl_[64][66];
    int j = threadIdx.x & 63, i0 = threadIdx.x >> 6;
    for (int i = i0; i < 64; i += 4) {
        float v = x[((size_t)b * C_ + c0 + i) * N_ + n0 + j];
        u16 h, l;
        split_bf(v, h, l);
        th_[i][j] = h;
        tl_[i][j] = l;
    }
    __syncthreads();
    for (int i = i0; i < 64; i += 4) {
        size_t o = ((size_t)b * N_ + n0 + i) * C_ + c0 + j;
        xbt_h[o] = th_[j][i];
        xbt_l[o] = tl_[j][i];
    }
}

// ---------------- projection GEMM (split precision): [384x256] @ [256x4096] ----------------
__global__ __launch_bounds__(256) void k_proj(
    const u16* __restrict__ Wcat_h, const u16* __restrict__ Wcat_l,
    const float* __restrict__ bcat,
    const u16* __restrict__ xbt_h, const u16* __restrict__ xbt_l,
    u16* __restrict__ th_h, u16* __restrict__ th_l,
    u16* __restrict__ pf_h, u16* __restrict__ pf_l,
    u16* __restrict__ gf) {
    int bid = blockIdx.x;
    int b = bid / 96, rem = bid % 96, rt = rem >> 5, nt = rem & 31;
    int w = threadIdx.x >> 6, lane = threadIdx.x & 63;
    int l15 = lane & 15, g16 = lane >> 4;
    int wr = (w >> 1) * 64, wc = (w & 1) * 64;
    int rbase = rt * 128 + wr, nbase = nt * 128 + wc;
    f32x4 acc[4][4];
#pragma unroll
    for (int i = 0; i < 4; ++i)
#pragma unroll
        for (int j = 0; j < 4; ++j)
#pragma unroll
            for (int r = 0; r < 4; ++r) acc[i][j][r] = 0.f;
#pragma unroll
    for (int ks = 0; ks < 8; ++ks) {
        bf16x8 ah[4], al[4], bh[4], bl[4];
#pragma unroll
        for (int i = 0; i < 4; ++i) {
            size_t o = (size_t)(rbase + i * 16 + l15) * 256 + ks * 32 + g16 * 8;
            ah[i] = ldb8(&Wcat_h[o]);
            al[i] = ldb8(&Wcat_l[o]);
        }
#pragma unroll
        for (int j = 0; j < 4; ++j) {
            size_t o = ((size_t)b * N_ + nbase + j * 16 + l15) * 256 + ks * 32 + g16 * 8;
            bh[j] = ldb8(&xbt_h[o]);
            bl[j] = ldb8(&xbt_l[o]);
        }
#pragma unroll
        for (int i = 0; i < 4; ++i)
#pragma unroll
            for (int j = 0; j < 4; ++j) {
                acc[i][j] = MFMA(ah[i], bh[j], acc[i][j]);
                acc[i][j] = MFMA(ah[i], bl[j], acc[i][j]);
                acc[i][j] = MFMA(al[i], bh[j], acc[i][j]);
            }
    }
#pragma unroll
    for (int i = 0; i < 4; ++i) {
        int lrow = wr + i * 16 + g16 * 4;
#pragma unroll
        for (int j = 0; j < 4; ++j) {
            int n = nbase + j * 16 + l15;
            size_t o = ((size_t)b * N_ + n) * CI_ + lrow;
            if (rt == 2) {
                u16x4 pk;
#pragma unroll
                for (int r = 0; r < 4; ++r)
                    pk[r] = f2bf(acc[i][j][r] + bcat[256 + lrow + r]);
                *reinterpret_cast<u16x4*>(&gf[o]) = pk;
            } else {
                u16x4 ph, pl;
#pragma unroll
                for (int r = 0; r < 4; ++r) {
                    float v = acc[i][j][r] + bcat[rt * 128 + lrow + r];
                    u16 hh, ll;
                    split_bf(v, hh, ll);
                    ph[r] = hh;
                    pl[r] = ll;
                }
                u16* dh = (rt == 0) ? th_h : pf_h;
                u16* dl = (rt == 0) ? th_l : pf_l;
                *reinterpret_cast<u16x4*>(&dh[o]) = ph;
                *reinterpret_cast<u16x4*>(&dl[o]) = pl;
            }
        }
    }
}

// ---------------- 2x2 maxpool (split): pf[b][n][ci] -> pp[b][m][ci] ----------------
__global__ __launch_bounds__(256) void k_pool_phi(
    const u16* __restrict__ pf_h, const u16* __restrict__ pf_l,
    u16* __restrict__ pp_h, u16* __restrict__ pp_l) {
    int idx = blockIdx.x * 256 + threadIdx.x;  // 8*1024*16
    int b = idx >> 14, rem = idx & 16383, m = rem >> 4, c8 = rem & 15;
    int h2 = m >> 5, w2 = m & 31;
    int n00 = h2 * 128 + w2 * 2;
    size_t base = ((size_t)b * N_ + n00) * CI_ + c8 * 8;
    u16x8 h0 = *(const u16x8*)&pf_h[base];
    u16x8 h1 = *(const u16x8*)&pf_h[base + CI_];
    u16x8 h2v = *(const u16x8*)&pf_h[base + 64 * CI_];
    u16x8 h3 = *(const u16x8*)&pf_h[base + 65 * CI_];
    u16x8 l0 = *(const u16x8*)&pf_l[base];
    u16x8 l1 = *(const u16x8*)&pf_l[base + CI_];
    u16x8 l2 = *(const u16x8*)&pf_l[base + 64 * CI_];
    u16x8 l3 = *(const u16x8*)&pf_l[base + 65 * CI_];
    u16x8 oh, ol;
#pragma unroll
    for (int e = 0; e < 8; ++e) {
        float v0 = bf2f(h0[e]) + bf2f(l0[e]);
        float v1 = bf2f(h1[e]) + bf2f(l1[e]);
        float v2 = bf2f(h2v[e]) + bf2f(l2[e]);
        float v3 = bf2f(h3[e]) + bf2f(l3[e]);
        float mx = fmaxf(fmaxf(v0, v1), fmaxf(v2, v3));
        u16 hh, ll;
        split_bf(mx, hh, ll);
        oh[e] = hh;
        ol[e] = ll;
    }
    size_t od = ((size_t)b * M_ + m) * CI_ + c8 * 8;
    *(u16x8*)&pp_h[od] = oh;
    *(u16x8*)&pp_l[od] = ol;
}

// ---------------- 2x2 maxpool + transpose: gf[b][n][ci] -> gp[b][ci][m] ----------------
__global__ __launch_bounds__(128) void k_pool_g(const u16* __restrict__ gf, u16* __restrict__ gp) {
    int bid = blockIdx.x;
    int b = bid >> 5, h2 = bid & 31;
    __shared__ u16 t[128][40];
    int tid = threadIdx.x;  // 128 threads, tid = ci
    for (int w2 = 0; w2 < 32; ++w2) {
        int n00 = h2 * 128 + w2 * 2;
        const u16* base = &gf[((size_t)b * N_ + n00) * CI_ + tid];
        float v = fmaxf(fmaxf(bf2f(base[0]), bf2f(base[CI_])),
                        fmaxf(bf2f(base[64 * CI_]), bf2f(base[65 * CI_])));
        t[tid][w2] = f2bf(v);
    }
    u16* dst = &gp[((size_t)b * CI_ + tid) * M_ + h2 * 32];
#pragma unroll
    for (int w2 = 0; w2 < 32; w2 += 8) *(u16x8*)&dst[w2] = *(u16x8*)&t[tid][w2];
}

// ---------------- flash attention: y^T = softmax(theta^T phi) g^T ----------------
__global__ __launch_bounds__(256) void k_attn(
    const u16* __restrict__ th_h, const u16* __restrict__ th_l,
    const u16* __restrict__ pp_h, const u16* __restrict__ pp_l,
    const u16* __restrict__ gp, u16* __restrict__ yt) {
    int bid = blockIdx.x;
    int b = bid >> 6, nt = bid & 63;
    int w = threadIdx.x >> 6, lane = threadIdx.x & 63;
    int l15 = lane & 15, g16 = lane >> 4;
    int n = nt * 64 + w * 16 + l15;
    __shared__ u16 plds[4][16][32];

    bf16x8 qh[4], ql[4];
    size_t qbase = ((size_t)b * N_ + n) * CI_;
#pragma unroll
    for (int ks = 0; ks < 4; ++ks) {
        qh[ks] = ldb8(&th_h[qbase + ks * 32 + g16 * 8]);
        ql[ks] = ldb8(&th_l[qbase + ks * 32 + g16 * 8]);
    }

    f32x4 o[8];
#pragma unroll
    for (int ct = 0; ct < 8; ++ct)
#pragma unroll
        for (int r = 0; r < 4; ++r) o[ct][r] = 0.f;
    float mrun = -1e30f, lrun = 0.f;

    for (int it = 0; it < 32; ++it) {
        int m0 = it * 32;
        f32x4 s0 = {0.f, 0.f, 0.f, 0.f}, s1 = {0.f, 0.f, 0.f, 0.f};
#pragma unroll
        for (int ks = 0; ks < 4; ++ks) {
            size_t o0 = ((size_t)b * M_ + m0 + l15) * CI_ + ks * 32 + g16 * 8;
            size_t o1 = ((size_t)b * M_ + m0 + 16 + l15) * CI_ + ks * 32 + g16 * 8;
            bf16x8 a0h = ldb8(&pp_h[o0]), a0l = ldb8(&pp_l[o0]);
            bf16x8 a1h = ldb8(&pp_h[o1]), a1l = ldb8(&pp_l[o1]);
            s0 = MFMA(a0h, qh[ks], s0);
            s0 = MFMA(a0h, ql[ks], s0);
            s0 = MFMA(a0l, qh[ks], s0);
            s1 = MFMA(a1h, qh[ks], s1);
            s1 = MFMA(a1h, ql[ks], s1);
            s1 = MFMA(a1l, qh[ks], s1);
        }
        // online softmax over m (per column n = l15)
        float pm = s0[0];
#pragma unroll
        for (int r = 1; r < 4; ++r) pm = fmaxf(pm, s0[r]);
#pragma unroll
        for (int r = 0; r < 4; ++r) pm = fmaxf(pm, s1[r]);
        pm = fmaxf(pm, __shfl_xor(pm, 16));
        pm = fmaxf(pm, __shfl_xor(pm, 32));
        float mnew = fmaxf(mrun, pm);
        float sc = __expf(mrun - mnew);
        float p[8];
        float ls = 0.f;
#pragma unroll
        for (int r = 0; r < 4; ++r) { p[r] = __expf(s0[r] - mnew); ls += p[r]; }
#pragma unroll
        for (int r = 0; r < 4; ++r) { p[4 + r] = __expf(s1[r] - mnew); ls += p[4 + r]; }
        ls += __shfl_xor(ls, 16);
        ls += __shfl_xor(ls, 32);
        lrun = lrun * sc + ls;
        mrun = mnew;
#pragma unroll
        for (int ct = 0; ct < 8; ++ct)
#pragma unroll
            for (int r = 0; r < 4; ++r) o[ct][r] *= sc;
        // P (lane-local, S^T layout) -> LDS -> P^T B-fragment
        u16x4 pk0, pk1;
#pragma unroll
        for (int r = 0; r < 4; ++r) { pk0[r] = f2bf(p[r]); pk1[r] = f2bf(p[4 + r]); }
        *reinterpret_cast<u16x4*>(&plds[w][l15][g16 * 4]) = pk0;
        *reinterpret_cast<u16x4*>(&plds[w][l15][16 + g16 * 4]) = pk1;
        asm volatile("s_waitcnt lgkmcnt(0)" ::: "memory");
        bf16x8 pfr = ldb8(&plds[w][l15][g16 * 8]);
#pragma unroll
        for (int ct = 0; ct < 8; ++ct) {
            bf16x8 gfr = ldb8(&gp[((size_t)b * CI_ + ct * 16 + l15) * M_ + m0 + g16 * 8]);
            o[ct] = MFMA(gfr, pfr, o[ct]);
        }
    }
    float linv = 1.f / lrun;
#pragma unroll
    for (int ct = 0; ct < 8; ++ct) {
        u16x4 pk;
#pragma unroll
        for (int r = 0; r < 4; ++r) pk[r] = f2bf(o[ct][r] * linv);
        *reinterpret_cast<u16x4*>(&yt[((size_t)b * N_ + n) * CI_ + ct * 16 + g16 * 4]) = pk;
    }
}

// ---------------- W conv GEMM + BN stats (z stored fp32) ----------------
__global__ __launch_bounds__(256) void k_wconv(
    const u16* __restrict__ Wwb, const float* __restrict__ Wb,
    const u16* __restrict__ yt, float* __restrict__ z,
    float* __restrict__ ssum, float* __restrict__ ssq) {
    int bid = blockIdx.x;
    int b = bid >> 6, rem = bid & 63, rt = rem >> 5, nt = rem & 31;
    int w = threadIdx.x >> 6, lane = threadIdx.x & 63;
    int l15 = lane & 15, g16 = lane >> 4;
    int cbase = rt * 128 + (w >> 1) * 64, nbase = nt * 128 + (w & 1) * 64;
    f32x4 acc[4][4];
#pragma unroll
    for (int i = 0; i < 4; ++i)
#pragma unroll
        for (int j = 0; j < 4; ++j)
#pragma unroll
            for (int r = 0; r < 4; ++r) acc[i][j][r] = 0.f;
#pragma unroll
    for (int ks = 0; ks < 4; ++ks) {
        bf16x8 a[4], bb[4];
#pragma unroll
        for (int i = 0; i < 4; ++i)
            a[i] = ldb8(&Wwb[(size_t)(cbase + i * 16 + l15) * 128 + ks * 32 + g16 * 8]);
#pragma unroll
        for (int j = 0; j < 4; ++j)
            bb[j] = ldb8(&yt[((size_t)b * N_ + nbase + j * 16 + l15) * CI_ + ks * 32 + g16 * 8]);
#pragma unroll
        for (int i = 0; i < 4; ++i)
#pragma unroll
            for (int j = 0; j < 4; ++j) acc[i][j] = MFMA(a[i], bb[j], acc[i][j]);
    }
#pragma unroll
    for (int i = 0; i < 4; ++i) {
#pragma unroll
        for (int r = 0; r < 4; ++r) {
            int ch = cbase + i * 16 + g16 * 4 + r;
            float bias = Wb[ch];
            float s = 0.f, q = 0.f;
#pragma unroll
            for (int j = 0; j < 4; ++j) {
                float v = acc[i][j][r] + bias;
                z[((size_t)b * C_ + ch) * N_ + nbase + j * 16 + l15] = v;
                s += v;
                q += v * v;
            }
            s += __shfl_xor(s, 1); q += __shfl_xor(q, 1);
            s += __shfl_xor(s, 2); q += __shfl_xor(q, 2);
            s += __shfl_xor(s, 4); q += __shfl_xor(q, 4);
            s += __shfl_xor(s, 8); q += __shfl_xor(q, 8);
            if (l15 == 0) {
                atomicAdd(&ssum[ch], s);
                atomicAdd(&ssq[ch], q);
            }
        }
    }
}

// ---------------- BN finalize ----------------
__global__ __launch_bounds__(256) void k_meanvar(
    const float* __restrict__ ssum, const float* __restrict__ ssq,
    const float* __restrict__ gamma, const float* __restrict__ beta,
    float* __restrict__ bnp) {
    int c = threadIdx.x;
    const float inv_n = 1.f / 32768.f;
    float mean = ssum[c] * inv_n;
    float var = ssq[c] * inv_n - mean * mean;
    float sc = gamma[c] * rsqrtf(var + 1e-5f);
    bnp[c] = sc;
    bnp[256 + c] = beta[c] - mean * sc;
}

// ---------------- apply BN + residual ----------------
__global__ __launch_bounds__(256) void k_final(
    const float* __restrict__ x, const float* __restrict__ z,
    const float* __restrict__ bnp, float* __restrict__ out) {
    int i4 = blockIdx.x * 256 + threadIdx.x;
    size_t flat = (size_t)i4 * 4;
    int c = (int)((flat >> 12) & 255);
    float sc = bnp[c], sh = bnp[256 + c];
    float4 xx = *(const float4*)&x[flat];
    float4 zz = *(const float4*)&z[flat];
    float4 oo;
    oo.x = xx.x + zz.x * sc + sh;
    oo.y = xx.y + zz.y * sc + sh;
    oo.z = xx.z + zz.z * sc + sh;
    oo.w = xx.w + zz.w * sc + sh;
    *(float4*)&out[flat] = oo;
}

extern "C" void kernel_launch(void* const* d_in, const int* in_sizes, int n_in,
                              void* d_out, int out_size, void* d_ws, size_t ws_size,
                              hipStream_t stream) {
    const float* x     = (const float*)d_in[0];
    const float* tw    = (const float*)d_in[1];
    const float* tb    = (const float*)d_in[2];
    const float* pw    = (const float*)d_in[3];
    const float* pb    = (const float*)d_in[4];
    const float* gw    = (const float*)d_in[5];
    const float* gb    = (const float*)d_in[6];
    const float* Ww    = (const float*)d_in[7];
    const float* Wb    = (const float*)d_in[8];
    const float* gamma = (const float*)d_in[9];
    const float* beta  = (const float*)d_in[10];
    float* out = (float*)d_out;

    char* p = (char*)d_ws;
    auto alloc = [&](size_t bytes) {
        char* r = p;
        p += (bytes + 255) & ~(size_t)255;
        return r;
    };
    u16* xbt_h  = (u16*)alloc((size_t)B_ * N_ * C_ * 2);   // 16 MB (dead after k_proj)
    u16* xbt_l  = (u16*)alloc((size_t)B_ * N_ * C_ * 2);   // 16 MB (dead after k_proj)
    u16* th_h   = (u16*)alloc((size_t)B_ * N_ * CI_ * 2);  // 8 MB (dead after k_attn)
    u16* th_l   = (u16*)alloc((size_t)B_ * N_ * CI_ * 2);
    u16* pf_h   = (u16*)alloc((size_t)B_ * N_ * CI_ * 2);
    u16* pf_l   = (u16*)alloc((size_t)B_ * N_ * CI_ * 2);
    u16* gf     = (u16*)alloc((size_t)B_ * N_ * CI_ * 2);
    u16* pp_h   = (u16*)alloc((size_t)B_ * M_ * CI_ * 2);
    u16* pp_l   = (u16*)alloc((size_t)B_ * M_ * CI_ * 2);
    u16* gp     = (u16*)alloc((size_t)B_ * M_ * CI_ * 2);
    u16* yt     = (u16*)alloc((size_t)B_ * N_ * CI_ * 2);
    u16* Wcat_h = (u16*)alloc(384 * 256 * 2);
    u16* Wcat_l = (u16*)alloc(384 * 256 * 2);
    u16* Wwb    = (u16*)alloc(256 * 128 * 2);
    float* bcat = (float*)alloc(384 * 4);
    float* ssum = (float*)alloc(256 * 4);
    float* ssq  = (float*)alloc(256 * 4);
    float* bnp  = (float*)alloc(512 * 4);
    // z (fp32, 33.5 MB) aliases xbt_h+xbt_l (32 MB) + head of th_h (1.5 MB):
    // all dead by the time k_wconv writes z (after k_attn).
    float* z = (float*)xbt_h;

    (void)hipMemsetAsync(ssum, 0, 256 * 4, stream);
    (void)hipMemsetAsync(ssq, 0, 256 * 4, stream);

    k_prep<<<514, 256, 0, stream>>>(tw, tb, pw, pb, gw, gb, Ww, Wcat_h, Wcat_l, bcat, Wwb);
    k_tx<<<2048, 256, 0, stream>>>(x, xbt_h, xbt_l);
    k_proj<<<768, 256, 0, stream>>>(Wcat_h, Wcat_l, bcat, xbt_h, xbt_l,
                                    th_h, th_l, pf_h, pf_l, gf);
    k_pool_phi<<<512, 256, 0, stream>>>(pf_h, pf_l, pp_h, pp_l);
    k_pool_g<<<256, 128, 0, stream>>>(gf, gp);
    k_attn<<<512, 256, 0, stream>>>(th_h, th_l, pp_h, pp_l, gp, yt);
    k_wconv<<<512, 256, 0, stream>>>(Wwb, Wb, yt, z, ssum, ssq);
    k_meanvar<<<1, 256, 0, stream>>>(ssum, ssq, gamma, beta, bnp);
    k_final<<<8192, 256, 0, stream>>>(x, z, bnp, out);
}

// Round 4
// 226.116 us; speedup vs baseline: 1.6033x; 1.6033x over previous
//
#include <hip/hip_runtime.h>

#define B_ 8
#define C_ 256
#define CI_ 128
#define N_ 4096
#define M_ 1024

typedef unsigned short u16;
typedef unsigned int u32;
typedef __bf16 bf16x8 __attribute__((ext_vector_type(8)));
typedef _Float16 f16x8 __attribute__((ext_vector_type(8)));
typedef float f32x4 __attribute__((ext_vector_type(4)));
typedef u16 u16x4 __attribute__((ext_vector_type(4)));
typedef u16 u16x8 __attribute__((ext_vector_type(8)));

__device__ __forceinline__ float bf2f(u16 u) {
    u32 i = ((u32)u) << 16;
    float f;
    __builtin_memcpy(&f, &i, 4);
    return f;
}
__device__ __forceinline__ u16 f2bf(float f) {
    u32 i;
    __builtin_memcpy(&i, &f, 4);
    u32 r = (i + 0x7fffu + ((i >> 16) & 1u)) >> 16;
    return (u16)r;
}
__device__ __forceinline__ u16 f2h(float f) {
    _Float16 h = (_Float16)f;
    u16 u;
    __builtin_memcpy(&u, &h, 2);
    return u;
}
__device__ __forceinline__ float h2f(u16 u) {
    _Float16 h;
    __builtin_memcpy(&h, &u, 2);
    return (float)h;
}
__device__ __forceinline__ void split_bf(float v, u16& hi, u16& lo) {
    hi = f2bf(v);
    lo = f2bf(v - bf2f(hi));
}
__device__ __forceinline__ bf16x8 ldb8(const u16* p) {
    return *reinterpret_cast<const bf16x8*>(p);
}
__device__ __forceinline__ f16x8 ldh8(const u16* p) {
    return *reinterpret_cast<const f16x8*>(p);
}
__device__ __forceinline__ f32x4 MFMAB(bf16x8 a, bf16x8 b, f32x4 c) {
    return __builtin_amdgcn_mfma_f32_16x16x32_bf16(a, b, c, 0, 0, 0);
}
__device__ __forceinline__ f32x4 MFMAH(f16x8 a, f16x8 b, f32x4 c) {
    return __builtin_amdgcn_mfma_f32_16x16x32_f16(a, b, c, 0, 0, 0);
}

// fragment-linear offset helpers (element index into u16 array)
// A/B-frag tile stream: [tile16][ks][lane(64)][8] ; lane = g16*16 + l15
// value at (row-in-16 = l15, k = ks*32 + g16*8 + e)

// ---------------- weight prep ----------------
__global__ __launch_bounds__(256) void k_prep(
    const float* __restrict__ tw, const float* __restrict__ tb,
    const float* __restrict__ pw, const float* __restrict__ pb,
    const float* __restrict__ gw, const float* __restrict__ gb,
    const float* __restrict__ Ww,
    u16* __restrict__ wcf_h, u16* __restrict__ wcf_l,
    float* __restrict__ bcat, u16* __restrict__ wwf) {
    int idx = blockIdx.x * 256 + threadIdx.x;
    if (idx < 384 * 256) {
        int r = idx >> 8, c = idx & 255;
        float v = (r < 128) ? tw[r * 256 + c]
                : (r < 256) ? pw[(r - 128) * 256 + c]
                            : gw[(r - 256) * 256 + c];
        u16 h, l;
        split_bf(v, h, l);
        size_t off = (size_t)((r >> 4) * 8 + (c >> 5)) * 512 +
                     (((c >> 3) & 3) * 16 + (r & 15)) * 8 + (c & 7);
        wcf_h[off] = h;
        wcf_l[off] = l;
    } else if (idx < 384 * 256 + 256 * 128) {
        int k2 = idx - 384 * 256;
        int c = k2 >> 7, k = k2 & 127;
        size_t off = (size_t)((c >> 4) * 4 + (k >> 5)) * 512 +
                     (((k >> 3) & 3) * 16 + (c & 15)) * 8 + (k & 7);
        wwf[off] = f2h(Ww[k2]);
    } else if (idx < 384 * 256 + 256 * 128 + 384) {
        int r = idx - (384 * 256 + 256 * 128);
        bcat[r] = (r < 128) ? tb[r] : (r < 256) ? pb[r - 128] : gb[r - 256];
    }
}

// ---------------- x (B,C,N) fp32 -> fragment-linear split bf16 ----------------
__global__ __launch_bounds__(256) void k_tx(const float* __restrict__ x,
                                            u16* __restrict__ xbf_h, u16* __restrict__ xbf_l) {
    int bid = blockIdx.x;
    int b = bid >> 8, rem = bid & 255, nt = rem >> 2, ct = rem & 3;
    int n0 = nt * 64, c0 = ct * 64;
    __shared__ u16 th_[64][66];
    __shared__ u16 tl_[64][66];
    int j = threadIdx.x & 63, i0 = threadIdx.x >> 6;
    for (int i = i0; i < 64; i += 4) {
        float v = x[((size_t)b * C_ + c0 + i) * N_ + n0 + j];
        u16 h, l;
        split_bf(v, h, l);
        th_[i][j] = h;
        tl_[i][j] = l;
    }
    __syncthreads();
    int w = threadIdx.x >> 6, lane = threadIdx.x & 63;
    int l15 = lane & 15, g16 = lane >> 4;
    int s = w;  // sub n-16-tile
#pragma unroll
    for (int kk = 0; kk < 2; ++kk) {
        u16x8 hv, lv;
#pragma unroll
        for (int e = 0; e < 8; ++e) {
            hv[e] = th_[kk * 32 + g16 * 8 + e][s * 16 + l15];
            lv[e] = tl_[kk * 32 + g16 * 8 + e][s * 16 + l15];
        }
        size_t off = ((size_t)(b * 256 + (n0 >> 4) + s) * 8 + (c0 >> 5) + kk) * 512 +
                     (size_t)lane * 8;
        *(u16x8*)&xbf_h[off] = hv;
        *(u16x8*)&xbf_l[off] = lv;
    }
}

// ---------------- projection GEMM (split-bf16 compute, fp16 out) ----------------
__global__ __launch_bounds__(256) void k_proj(
    const u16* __restrict__ wcf_h, const u16* __restrict__ wcf_l,
    const float* __restrict__ bcat,
    const u16* __restrict__ xbf_h, const u16* __restrict__ xbf_l,
    u16* __restrict__ thf, u16* __restrict__ pf, u16* __restrict__ gf) {
    int bid = blockIdx.x;
    int b = bid / 96, rem = bid % 96, rt = rem >> 5, nt = rem & 31;
    int w = threadIdx.x >> 6, lane = threadIdx.x & 63;
    int l15 = lane & 15, g16 = lane >> 4;
    int wr = (w >> 1) * 64, wc = (w & 1) * 64;
    int rbase = rt * 128 + wr, nbase = nt * 128 + wc;
    f32x4 acc[4][4];
#pragma unroll
    for (int i = 0; i < 4; ++i)
#pragma unroll
        for (int j = 0; j < 4; ++j)
#pragma unroll
            for (int r = 0; r < 4; ++r) acc[i][j][r] = 0.f;
#pragma unroll
    for (int ks = 0; ks < 8; ++ks) {
        bf16x8 ah[4], al[4], bh[4], bl[4];
#pragma unroll
        for (int i = 0; i < 4; ++i) {
            size_t o = ((size_t)((rbase >> 4) + i) * 8 + ks) * 512 + (size_t)lane * 8;
            ah[i] = ldb8(&wcf_h[o]);
            al[i] = ldb8(&wcf_l[o]);
        }
#pragma unroll
        for (int j = 0; j < 4; ++j) {
            size_t o = ((size_t)(b * 256 + (nbase >> 4) + j) * 8 + ks) * 512 + (size_t)lane * 8;
            bh[j] = ldb8(&xbf_h[o]);
            bl[j] = ldb8(&xbf_l[o]);
        }
#pragma unroll
        for (int i = 0; i < 4; ++i)
#pragma unroll
            for (int j = 0; j < 4; ++j) {
                acc[i][j] = MFMAB(ah[i], bh[j], acc[i][j]);
                acc[i][j] = MFMAB(ah[i], bl[j], acc[i][j]);
                acc[i][j] = MFMAB(al[i], bh[j], acc[i][j]);
            }
    }
#pragma unroll
    for (int i = 0; i < 4; ++i) {
        int lrow = wr + i * 16 + g16 * 4;  // ci0 (4 consecutive)
#pragma unroll
        for (int j = 0; j < 4; ++j) {
            int n = nbase + j * 16 + l15;
            u16x4 pk;
#pragma unroll
            for (int r = 0; r < 4; ++r)
                pk[r] = f2h(acc[i][j][r] + bcat[rt * 128 + lrow + r]);
            if (rt == 0) {
                size_t off = ((size_t)(b * 256 + (nbase >> 4) + j) * 4 + (lrow >> 5)) * 512 +
                             (((lrow >> 3) & 3) * 16 + l15) * 8 + (lrow & 7);
                *reinterpret_cast<u16x4*>(&thf[off]) = pk;
            } else {
                u16* dst = (rt == 1) ? pf : gf;
                *reinterpret_cast<u16x4*>(&dst[((size_t)b * N_ + n) * CI_ + lrow]) = pk;
            }
        }
    }
}

// ---------------- 2x2 maxpool phi: pf[b][n][ci] fp16 -> ppf fragment-linear ----------------
__global__ __launch_bounds__(256) void k_pool_phi(const u16* __restrict__ pf,
                                                  u16* __restrict__ ppf) {
    int idx = blockIdx.x * 256 + threadIdx.x;  // 8*1024*16
    int b = idx >> 14, rem = idx & 16383, m = rem >> 4, c8 = rem & 15;
    int h2 = m >> 5, w2 = m & 31;
    int n00 = h2 * 128 + w2 * 2;
    size_t base = ((size_t)b * N_ + n00) * CI_ + c8 * 8;
    u16x8 v0 = *(const u16x8*)&pf[base];
    u16x8 v1 = *(const u16x8*)&pf[base + CI_];
    u16x8 v2 = *(const u16x8*)&pf[base + 64 * CI_];
    u16x8 v3 = *(const u16x8*)&pf[base + 65 * CI_];
    u16x8 o;
#pragma unroll
    for (int e = 0; e < 8; ++e) {
        float mx = fmaxf(fmaxf(h2f(v0[e]), h2f(v1[e])), fmaxf(h2f(v2[e]), h2f(v3[e])));
        o[e] = f2h(mx);
    }
    // it = m>>5, half = (m>>4)&1, l15 = m&15, ks = c8>>2, g16 = c8&3
    size_t off = ((size_t)(((b * 32 + (m >> 5)) * 2 + ((m >> 4) & 1)) * 4 + (c8 >> 2)) * 64 +
                  (c8 & 3) * 16 + (m & 15)) * 8;
    *(u16x8*)&ppf[off] = o;
}

// ---------------- 2x2 maxpool g + fragment-linear transpose ----------------
__global__ __launch_bounds__(128) void k_pool_g(const u16* __restrict__ gf,
                                                u16* __restrict__ gpf) {
    int bid = blockIdx.x;
    int b = bid >> 5, h2 = bid & 31;
    int ci = threadIdx.x;  // 128 threads
    int ct = ci >> 4, l15 = ci & 15;
#pragma unroll
    for (int wg = 0; wg < 4; ++wg) {
        u16x8 o;
#pragma unroll
        for (int e = 0; e < 8; ++e) {
            int w2 = wg * 8 + e;
            int n00 = h2 * 128 + w2 * 2;
            const u16* base = &gf[((size_t)b * N_ + n00) * CI_ + ci];
            float v = fmaxf(fmaxf(h2f(base[0]), h2f(base[CI_])),
                            fmaxf(h2f(base[64 * CI_]), h2f(base[65 * CI_])));
            o[e] = f2h(v);
        }
        size_t off = ((size_t)((b * 32 + h2) * 8 + ct) * 64 + wg * 16 + l15) * 8;
        *(u16x8*)&gpf[off] = o;
    }
}

// ---------------- flash attention (split-m=2, fp16, frag-linear) ----------------
__global__ __launch_bounds__(256) void k_attn(
    const u16* __restrict__ thf, const u16* __restrict__ ppf,
    const u16* __restrict__ gpf,
    u16* __restrict__ of_h, u16* __restrict__ of_l, float2* __restrict__ ml) {
    int bid = blockIdx.x;
    int b = bid & 7, r = bid >> 3;   // b = bid%8 -> same-b blocks share an XCD
    int sp = r >> 6, nt = r & 63;
    int w = threadIdx.x >> 6, lane = threadIdx.x & 63;
    int l15 = lane & 15, g16 = lane >> 4;
    int n = nt * 64 + w * 16 + l15;
    int t16 = nt * 4 + w;
    __shared__ u16 plds[4][16][40];  // padded: conflict-free transpose

    f16x8 qf[4];
#pragma unroll
    for (int ks = 0; ks < 4; ++ks)
        qf[ks] = ldh8(&thf[((size_t)(b * 256 + t16) * 4 + ks) * 512 + (size_t)lane * 8]);

    f32x4 o[8];
#pragma unroll
    for (int ct = 0; ct < 8; ++ct)
#pragma unroll
        for (int rr = 0; rr < 4; ++rr) o[ct][rr] = 0.f;
    float mrun = -1e30f, lrun = 0.f;

    for (int it = 0; it < 16; ++it) {
        int itg = sp * 16 + it;
        f16x8 pa0[4], pa1[4], gv[8];
#pragma unroll
        for (int ks = 0; ks < 4; ++ks) {
            size_t p0 = ((size_t)((b * 32 + itg) * 2 + 0) * 4 + ks) * 512 + (size_t)lane * 8;
            size_t p1 = ((size_t)((b * 32 + itg) * 2 + 1) * 4 + ks) * 512 + (size_t)lane * 8;
            pa0[ks] = ldh8(&ppf[p0]);
            pa1[ks] = ldh8(&ppf[p1]);
        }
#pragma unroll
        for (int ct = 0; ct < 8; ++ct)
            gv[ct] = ldh8(&gpf[((size_t)(b * 32 + itg) * 8 + ct) * 512 + (size_t)lane * 8]);

        f32x4 s0 = {0.f, 0.f, 0.f, 0.f}, s1 = {0.f, 0.f, 0.f, 0.f};
#pragma unroll
        for (int ks = 0; ks < 4; ++ks) {
            s0 = MFMAH(pa0[ks], qf[ks], s0);
            s1 = MFMAH(pa1[ks], qf[ks], s1);
        }
        float pm = s0[0];
#pragma unroll
        for (int rr = 1; rr < 4; ++rr) pm = fmaxf(pm, s0[rr]);
#pragma unroll
        for (int rr = 0; rr < 4; ++rr) pm = fmaxf(pm, s1[rr]);
        pm = fmaxf(pm, __shfl_xor(pm, 16));
        pm = fmaxf(pm, __shfl_xor(pm, 32));
        float mnew = fmaxf(mrun, pm);
        float sc = __expf(mrun - mnew);
        float p[8];
        float ls = 0.f;
#pragma unroll
        for (int rr = 0; rr < 4; ++rr) { p[rr] = __expf(s0[rr] - mnew); ls += p[rr]; }
#pragma unroll
        for (int rr = 0; rr < 4; ++rr) { p[4 + rr] = __expf(s1[rr] - mnew); ls += p[4 + rr]; }
        ls += __shfl_xor(ls, 16);
        ls += __shfl_xor(ls, 32);
        lrun = lrun * sc + ls;
        mrun = mnew;
#pragma unroll
        for (int ct = 0; ct < 8; ++ct)
#pragma unroll
            for (int rr = 0; rr < 4; ++rr) o[ct][rr] *= sc;
        u16x4 pk0, pk1;
#pragma unroll
        for (int rr = 0; rr < 4; ++rr) { pk0[rr] = f2h(p[rr]); pk1[rr] = f2h(p[4 + rr]); }
        *reinterpret_cast<u16x4*>(&plds[w][l15][g16 * 4]) = pk0;
        *reinterpret_cast<u16x4*>(&plds[w][l15][16 + g16 * 4]) = pk1;
        asm volatile("s_waitcnt lgkmcnt(0)" ::: "memory");
        f16x8 pfr = ldh8(&plds[w][l15][g16 * 8]);
#pragma unroll
        for (int ct = 0; ct < 8; ++ct) o[ct] = MFMAH(gv[ct], pfr, o[ct]);
    }
    size_t obase = ((size_t)(b * 2 + sp) * N_ + n) * CI_;
#pragma unroll
    for (int ct = 0; ct < 8; ++ct) {
        u16x4 hh, ll;
#pragma unroll
        for (int rr = 0; rr < 4; ++rr) {
            u16 a, bb;
            split_bf(o[ct][rr], a, bb);
            hh[rr] = a;
            ll[rr] = bb;
        }
        *reinterpret_cast<u16x4*>(&of_h[obase + ct * 16 + g16 * 4]) = hh;
        *reinterpret_cast<u16x4*>(&of_l[obase + ct * 16 + g16 * 4]) = ll;
    }
    if (g16 == 0) ml[(size_t)(b * 2 + sp) * N_ + n] = make_float2(mrun, lrun);
}

// ---------------- combine 2 splits -> ytf fp16 fragment-linear ----------------
__global__ __launch_bounds__(256) void k_combine(
    const u16* __restrict__ of_h, const u16* __restrict__ of_l,
    const float2* __restrict__ ml, u16* __restrict__ ytf) {
    int idx = blockIdx.x * 256 + threadIdx.x;  // 8*4096*16
    int b = idx >> 16, rem = idx & 65535, n = rem >> 4, c8 = rem & 15;
    float2 ml0 = ml[(size_t)(b * 2 + 0) * N_ + n];
    float2 ml1 = ml[(size_t)(b * 2 + 1) * N_ + n];
    float M = fmaxf(ml0.x, ml1.x);
    float w0 = __expf(ml0.x - M), w1 = __expf(ml1.x - M);
    float invL = 1.f / (w0 * ml0.y + w1 * ml1.y);
    float s0 = w0 * invL, s1 = w1 * invL;
    size_t b0 = ((size_t)(b * 2 + 0) * N_ + n) * CI_ + c8 * 8;
    size_t b1 = ((size_t)(b * 2 + 1) * N_ + n) * CI_ + c8 * 8;
    u16x8 h0 = *(const u16x8*)&of_h[b0], l0 = *(const u16x8*)&of_l[b0];
    u16x8 h1 = *(const u16x8*)&of_h[b1], l1 = *(const u16x8*)&of_l[b1];
    u16x8 y;
#pragma unroll
    for (int e = 0; e < 8; ++e) {
        float v = (bf2f(h0[e]) + bf2f(l0[e])) * s0 + (bf2f(h1[e]) + bf2f(l1[e])) * s1;
        y[e] = f2h(v);
    }
    size_t off = ((size_t)(b * 256 + (n >> 4)) * 4 + (c8 >> 2)) * 512 +
                 ((c8 & 3) * 16 + (n & 15)) * 8;
    *(u16x8*)&ytf[off] = y;
}

// ---------------- W conv GEMM (fp16) + BN stats ----------------
__global__ __launch_bounds__(256) void k_wconv(
    const u16* __restrict__ wwf, const float* __restrict__ Wb,
    const u16* __restrict__ ytf, float* __restrict__ z,
    float* __restrict__ ssum, float* __restrict__ ssq) {
    int bid = blockIdx.x;
    int b = bid >> 6, rem = bid & 63, rt = rem >> 5, nt = rem & 31;
    int w = threadIdx.x >> 6, lane = threadIdx.x & 63;
    int l15 = lane & 15, g16 = lane >> 4;
    int cbase = rt * 128 + (w >> 1) * 64, nbase = nt * 128 + (w & 1) * 64;
    f32x4 acc[4][4];
#pragma unroll
    for (int i = 0; i < 4; ++i)
#pragma unroll
        for (int j = 0; j < 4; ++j)
#pragma unroll
            for (int r = 0; r < 4; ++r) acc[i][j][r] = 0.f;
#pragma unroll
    for (int ks = 0; ks < 4; ++ks) {
        f16x8 a[4], bb[4];
#pragma unroll
        for (int i = 0; i < 4; ++i)
            a[i] = ldh8(&wwf[((size_t)((cbase >> 4) + i) * 4 + ks) * 512 + (size_t)lane * 8]);
#pragma unroll
        for (int j = 0; j < 4; ++j)
            bb[j] = ldh8(&ytf[((size_t)(b * 256 + (nbase >> 4) + j) * 4 + ks) * 512 +
                              (size_t)lane * 8]);
#pragma unroll
        for (int i = 0; i < 4; ++i)
#pragma unroll
            for (int j = 0; j < 4; ++j) acc[i][j] = MFMAH(a[i], bb[j], acc[i][j]);
    }
#pragma unroll
    for (int i = 0; i < 4; ++i) {
#pragma unroll
        for (int r = 0; r < 4; ++r) {
            int ch = cbase + i * 16 + g16 * 4 + r;
            float bias = Wb[ch];
            float s = 0.f, q = 0.f;
#pragma unroll
            for (int j = 0; j < 4; ++j) {
                float v = acc[i][j][r] + bias;
                z[((size_t)b * C_ + ch) * N_ + nbase + j * 16 + l15] = v;
                s += v;
                q += v * v;
            }
            s += __shfl_xor(s, 1); q += __shfl_xor(q, 1);
            s += __shfl_xor(s, 2); q += __shfl_xor(q, 2);
            s += __shfl_xor(s, 4); q += __shfl_xor(q, 4);
            s += __shfl_xor(s, 8); q += __shfl_xor(q, 8);
            if (l15 == 0) {
                atomicAdd(&ssum[ch], s);
                atomicAdd(&ssq[ch], q);
            }
        }
    }
}

// ---------------- BN finalize ----------------
__global__ __launch_bounds__(256) void k_meanvar(
    const float* __restrict__ ssum, const float* __restrict__ ssq,
    const float* __restrict__ gamma, const float* __restrict__ beta,
    float* __restrict__ bnp) {
    int c = threadIdx.x;
    const float inv_n = 1.f / 32768.f;
    float mean = ssum[c] * inv_n;
    float var = ssq[c] * inv_n - mean * mean;
    float sc = gamma[c] * rsqrtf(var + 1e-5f);
    bnp[c] = sc;
    bnp[256 + c] = beta[c] - mean * sc;
}

// ---------------- apply BN + residual ----------------
__global__ __launch_bounds__(256) void k_final(
    const float* __restrict__ x, const float* __restrict__ z,
    const float* __restrict__ bnp, float* __restrict__ out) {
    int i4 = blockIdx.x * 256 + threadIdx.x;
    size_t flat = (size_t)i4 * 4;
    int c = (int)((flat >> 12) & 255);
    float sc = bnp[c], sh = bnp[256 + c];
    float4 xx = *(const float4*)&x[flat];
    float4 zz = *(const float4*)&z[flat];
    float4 oo;
    oo.x = xx.x + zz.x * sc + sh;
    oo.y = xx.y + zz.y * sc + sh;
    oo.z = xx.z + zz.z * sc + sh;
    oo.w = xx.w + zz.w * sc + sh;
    *(float4*)&out[flat] = oo;
}

extern "C" void kernel_launch(void* const* d_in, const int* in_sizes, int n_in,
                              void* d_out, int out_size, void* d_ws, size_t ws_size,
                              hipStream_t stream) {
    const float* x     = (const float*)d_in[0];
    const float* tw    = (const float*)d_in[1];
    const float* tb    = (const float*)d_in[2];
    const float* pw    = (const float*)d_in[3];
    const float* pb    = (const float*)d_in[4];
    const float* gw    = (const float*)d_in[5];
    const float* gb    = (const float*)d_in[6];
    const float* Ww    = (const float*)d_in[7];
    const float* Wb    = (const float*)d_in[8];
    const float* gamma = (const float*)d_in[9];
    const float* beta  = (const float*)d_in[10];
    float* out = (float*)d_out;

    char* p = (char*)d_ws;
    auto alloc = [&](size_t bytes) {
        char* r = p;
        p += (bytes + 255) & ~(size_t)255;
        return r;
    };
    u16* xbf_h = (u16*)alloc((size_t)B_ * N_ * C_ * 2);      // 16 MB, dead after k_proj
    u16* xbf_l = (u16*)alloc((size_t)B_ * N_ * C_ * 2);      // 16 MB
    u16* thf   = (u16*)alloc((size_t)B_ * N_ * CI_ * 2);     // 8 MB, dead after k_attn
    u16* pf    = (u16*)alloc((size_t)B_ * N_ * CI_ * 2);     // 8 MB, dead after pool_phi
    u16* gf    = (u16*)alloc((size_t)B_ * N_ * CI_ * 2);     // 8 MB, dead after pool_g
    u16* ppf   = (u16*)alloc((size_t)B_ * M_ * CI_ * 2);     // 2 MB
    u16* gpf   = (u16*)alloc((size_t)B_ * M_ * CI_ * 2);     // 2 MB
    u16* of_l  = (u16*)alloc((size_t)2 * B_ * N_ * CI_ * 2); // 16 MB
    float2* ml = (float2*)alloc((size_t)2 * B_ * N_ * 8);    // 512 KB
    u16* ytf   = (u16*)alloc((size_t)B_ * N_ * CI_ * 2);     // 8 MB
    u16* wcf_h = (u16*)alloc(384 * 256 * 2);
    u16* wcf_l = (u16*)alloc(384 * 256 * 2);
    u16* wwf   = (u16*)alloc(256 * 128 * 2);
    float* bcat = (float*)alloc(384 * 4);
    float* ssum = (float*)alloc(256 * 4);
    float* ssq  = (float*)alloc(256 * 4);
    float* bnp  = (float*)alloc(512 * 4);
    // aliases (dead-region reuse):
    u16* of_h = pf;          // 16 MB over pf+gf (both dead before k_attn writes)
    float* z  = (float*)xbf_h;  // 33.5 MB over xbf_h+xbf_l+thf (dead before k_wconv)

    (void)hipMemsetAsync(ssum, 0, 256 * 4, stream);
    (void)hipMemsetAsync(ssq, 0, 256 * 4, stream);

    k_prep<<<514, 256, 0, stream>>>(tw, tb, pw, pb, gw, gb, Ww, wcf_h, wcf_l, bcat, wwf);
    k_tx<<<2048, 256, 0, stream>>>(x, xbf_h, xbf_l);
    k_proj<<<768, 256, 0, stream>>>(wcf_h, wcf_l, bcat, xbf_h, xbf_l, thf, pf, gf);
    k_pool_phi<<<512, 256, 0, stream>>>(pf, ppf);
    k_pool_g<<<256, 128, 0, stream>>>(gf, gpf);
    k_attn<<<1024, 256, 0, stream>>>(thf, ppf, gpf, of_h, of_l, ml);
    k_combine<<<2048, 256, 0, stream>>>(of_h, of_l, ml, ytf);
    k_wconv<<<512, 256, 0, stream>>>(wwf, Wb, ytf, z, ssum, ssq);
    k_meanvar<<<1, 256, 0, stream>>>(ssum, ssq, gamma, beta, bnp);
    k_final<<<8192, 256, 0, stream>>>(x, z, bnp, out);
}

// Round 5
// 148.786 us; speedup vs baseline: 2.4366x; 1.5197x over previous
//
#include <hip/hip_runtime.h>

#define B_ 8
#define C_ 256
#define CI_ 128
#define N_ 4096
#define M_ 1024

typedef unsigned short u16;
typedef unsigned int u32;
typedef __bf16 bf16x8 __attribute__((ext_vector_type(8)));
typedef _Float16 f16x8 __attribute__((ext_vector_type(8)));
typedef float f32x4 __attribute__((ext_vector_type(4)));
typedef u16 u16x4 __attribute__((ext_vector_type(4)));
typedef u16 u16x8 __attribute__((ext_vector_type(8)));

__device__ __forceinline__ float bf2f(u16 u) {
    u32 i = ((u32)u) << 16;
    float f;
    __builtin_memcpy(&f, &i, 4);
    return f;
}
__device__ __forceinline__ u16 f2bf(float f) {
    u32 i;
    __builtin_memcpy(&i, &f, 4);
    u32 r = (i + 0x7fffu + ((i >> 16) & 1u)) >> 16;
    return (u16)r;
}
__device__ __forceinline__ u16 f2h(float f) {
    _Float16 h = (_Float16)f;
    u16 u;
    __builtin_memcpy(&u, &h, 2);
    return u;
}
__device__ __forceinline__ float h2f(u16 u) {
    _Float16 h;
    __builtin_memcpy(&h, &u, 2);
    return (float)h;
}
__device__ __forceinline__ void split_bf(float v, u16& hi, u16& lo) {
    hi = f2bf(v);
    lo = f2bf(v - bf2f(hi));
}
__device__ __forceinline__ bf16x8 ldb8(const u16* p) {
    return *reinterpret_cast<const bf16x8*>(p);
}
__device__ __forceinline__ f16x8 ldh8(const u16* p) {
    return *reinterpret_cast<const f16x8*>(p);
}
__device__ __forceinline__ f32x4 MFMAB(bf16x8 a, bf16x8 b, f32x4 c) {
    return __builtin_amdgcn_mfma_f32_16x16x32_bf16(a, b, c, 0, 0, 0);
}
__device__ __forceinline__ f32x4 MFMAH(f16x8 a, f16x8 b, f32x4 c) {
    return __builtin_amdgcn_mfma_f32_16x16x32_f16(a, b, c, 0, 0, 0);
}

// fragment-linear layout: [tile16][ks][lane(64)][8]; value (row-in-16 = lane&15,
// k = ks*32 + (lane>>4)*8 + e). Same layout serves as A-frag (row) or B-frag (col).

// ---------------- weight prep ----------------
__global__ __launch_bounds__(256) void k_prep(
    const float* __restrict__ tw, const float* __restrict__ tb,
    const float* __restrict__ pw, const float* __restrict__ pb,
    const float* __restrict__ gw, const float* __restrict__ gb,
    const float* __restrict__ Ww,
    u16* __restrict__ wcf_h, u16* __restrict__ wcf_l,
    float* __restrict__ bcat, u16* __restrict__ wwf) {
    int idx = blockIdx.x * 256 + threadIdx.x;
    if (idx < 384 * 256) {
        int r = idx >> 8, c = idx & 255;
        float v = (r < 128) ? tw[r * 256 + c]
                : (r < 256) ? pw[(r - 128) * 256 + c]
                            : gw[(r - 256) * 256 + c];
        u16 h, l;
        split_bf(v, h, l);
        size_t off = (size_t)((r >> 4) * 8 + (c >> 5)) * 512 +
                     (((c >> 3) & 3) * 16 + (r & 15)) * 8 + (c & 7);
        wcf_h[off] = h;
        wcf_l[off] = l;
    } else if (idx < 384 * 256 + 256 * 128) {
        int k2 = idx - 384 * 256;
        int c = k2 >> 7, k = k2 & 127;
        size_t off = (size_t)((c >> 4) * 4 + (k >> 5)) * 512 +
                     (((k >> 3) & 3) * 16 + (c & 15)) * 8 + (k & 7);
        wwf[off] = f2h(Ww[k2]);
    } else if (idx < 384 * 256 + 256 * 128 + 384) {
        int r = idx - (384 * 256 + 256 * 128);
        bcat[r] = (r < 128) ? tb[r] : (r < 256) ? pb[r - 128] : gb[r - 256];
    }
}

// ---------------- x (B,C,N) fp32 -> fragment-linear split bf16 ----------------
__global__ __launch_bounds__(256) void k_tx(const float* __restrict__ x,
                                            u16* __restrict__ xbf_h, u16* __restrict__ xbf_l) {
    int bid = blockIdx.x;
    int b = bid >> 8, rem = bid & 255, nt = rem >> 2, ct = rem & 3;
    int n0 = nt * 64, c0 = ct * 64;
    __shared__ u16 th_[64][66];
    __shared__ u16 tl_[64][66];
    int j = threadIdx.x & 63, i0 = threadIdx.x >> 6;
    for (int i = i0; i < 64; i += 4) {
        float v = x[((size_t)b * C_ + c0 + i) * N_ + n0 + j];
        u16 h, l;
        split_bf(v, h, l);
        th_[i][j] = h;
        tl_[i][j] = l;
    }
    __syncthreads();
    int w = threadIdx.x >> 6, lane = threadIdx.x & 63;
    int l15 = lane & 15, g16 = lane >> 4;
    int s = w;
#pragma unroll
    for (int kk = 0; kk < 2; ++kk) {
        u16x8 hv, lv;
#pragma unroll
        for (int e = 0; e < 8; ++e) {
            hv[e] = th_[kk * 32 + g16 * 8 + e][s * 16 + l15];
            lv[e] = tl_[kk * 32 + g16 * 8 + e][s * 16 + l15];
        }
        size_t off = ((size_t)(b * 256 + (n0 >> 4) + s) * 8 + (c0 >> 5) + kk) * 512 +
                     (size_t)lane * 8;
        *(u16x8*)&xbf_h[off] = hv;
        *(u16x8*)&xbf_l[off] = lv;
    }
}

// ---------------- projection GEMM (split-bf16 compute, fp16 out) ----------------
__global__ __launch_bounds__(256) void k_proj(
    const u16* __restrict__ wcf_h, const u16* __restrict__ wcf_l,
    const float* __restrict__ bcat,
    const u16* __restrict__ xbf_h, const u16* __restrict__ xbf_l,
    u16* __restrict__ thf, u16* __restrict__ pf, u16* __restrict__ gf) {
    int bid = blockIdx.x;
    int b = bid / 96, rem = bid % 96, rt = rem >> 5, nt = rem & 31;
    int w = threadIdx.x >> 6, lane = threadIdx.x & 63;
    int l15 = lane & 15, g16 = lane >> 4;
    int wr = (w >> 1) * 64, wc = (w & 1) * 64;
    int rbase = rt * 128 + wr, nbase = nt * 128 + wc;
    f32x4 acc[4][4];
#pragma unroll
    for (int i = 0; i < 4; ++i)
#pragma unroll
        for (int j = 0; j < 4; ++j)
#pragma unroll
            for (int r = 0; r < 4; ++r) acc[i][j][r] = 0.f;
#pragma unroll
    for (int ks = 0; ks < 8; ++ks) {
        bf16x8 ah[4], al[4], bh[4], bl[4];
#pragma unroll
        for (int i = 0; i < 4; ++i) {
            size_t o = ((size_t)((rbase >> 4) + i) * 8 + ks) * 512 + (size_t)lane * 8;
            ah[i] = ldb8(&wcf_h[o]);
            al[i] = ldb8(&wcf_l[o]);
        }
#pragma unroll
        for (int j = 0; j < 4; ++j) {
            size_t o = ((size_t)(b * 256 + (nbase >> 4) + j) * 8 + ks) * 512 + (size_t)lane * 8;
            bh[j] = ldb8(&xbf_h[o]);
            bl[j] = ldb8(&xbf_l[o]);
        }
#pragma unroll
        for (int i = 0; i < 4; ++i)
#pragma unroll
            for (int j = 0; j < 4; ++j) {
                acc[i][j] = MFMAB(ah[i], bh[j], acc[i][j]);
                acc[i][j] = MFMAB(ah[i], bl[j], acc[i][j]);
                acc[i][j] = MFMAB(al[i], bh[j], acc[i][j]);
            }
    }
#pragma unroll
    for (int i = 0; i < 4; ++i) {
        int lrow = wr + i * 16 + g16 * 4;
#pragma unroll
        for (int j = 0; j < 4; ++j) {
            int n = nbase + j * 16 + l15;
            u16x4 pk;
#pragma unroll
            for (int r = 0; r < 4; ++r)
                pk[r] = f2h(acc[i][j][r] + bcat[rt * 128 + lrow + r]);
            if (rt == 0) {
                size_t off = ((size_t)(b * 256 + (nbase >> 4) + j) * 4 + (lrow >> 5)) * 512 +
                             (((lrow >> 3) & 3) * 16 + l15) * 8 + (lrow & 7);
                *reinterpret_cast<u16x4*>(&thf[off]) = pk;
            } else {
                u16* dst = (rt == 1) ? pf : gf;
                *reinterpret_cast<u16x4*>(&dst[((size_t)b * N_ + n) * CI_ + lrow]) = pk;
            }
        }
    }
}

// ---------------- 2x2 maxpool phi -> ppf fragment-linear ----------------
__global__ __launch_bounds__(256) void k_pool_phi(const u16* __restrict__ pf,
                                                  u16* __restrict__ ppf) {
    int idx = blockIdx.x * 256 + threadIdx.x;
    int b = idx >> 14, rem = idx & 16383, m = rem >> 4, c8 = rem & 15;
    int h2 = m >> 5, w2 = m & 31;
    int n00 = h2 * 128 + w2 * 2;
    size_t base = ((size_t)b * N_ + n00) * CI_ + c8 * 8;
    u16x8 v0 = *(const u16x8*)&pf[base];
    u16x8 v1 = *(const u16x8*)&pf[base + CI_];
    u16x8 v2 = *(const u16x8*)&pf[base + 64 * CI_];
    u16x8 v3 = *(const u16x8*)&pf[base + 65 * CI_];
    u16x8 o;
#pragma unroll
    for (int e = 0; e < 8; ++e) {
        float mx = fmaxf(fmaxf(h2f(v0[e]), h2f(v1[e])), fmaxf(h2f(v2[e]), h2f(v3[e])));
        o[e] = f2h(mx);
    }
    size_t off = ((size_t)(((b * 32 + (m >> 5)) * 2 + ((m >> 4) & 1)) * 4 + (c8 >> 2)) * 64 +
                  (c8 & 3) * 16 + (m & 15)) * 8;
    *(u16x8*)&ppf[off] = o;
}

// ---------------- 2x2 maxpool g + fragment-linear transpose ----------------
__global__ __launch_bounds__(128) void k_pool_g(const u16* __restrict__ gf,
                                                u16* __restrict__ gpf) {
    int bid = blockIdx.x;
    int b = bid >> 5, h2 = bid & 31;
    int ci = threadIdx.x;
    int ct = ci >> 4, l15 = ci & 15;
#pragma unroll
    for (int wg = 0; wg < 4; ++wg) {
        u16x8 o;
#pragma unroll
        for (int e = 0; e < 8; ++e) {
            int w2 = wg * 8 + e;
            int n00 = h2 * 128 + w2 * 2;
            const u16* base = &gf[((size_t)b * N_ + n00) * CI_ + ci];
            float v = fmaxf(fmaxf(h2f(base[0]), h2f(base[CI_])),
                            fmaxf(h2f(base[64 * CI_]), h2f(base[65 * CI_])));
            o[e] = f2h(v);
        }
        size_t off = ((size_t)((b * 32 + h2) * 8 + ct) * 64 + wg * 16 + l15) * 8;
        *(u16x8*)&gpf[off] = o;
    }
}

// ---------------- flash attention (split-m=2, fp16, frag-linear) ----------------
__global__ __launch_bounds__(256) void k_attn(
    const u16* __restrict__ thf, const u16* __restrict__ ppf,
    const u16* __restrict__ gpf,
    u16* __restrict__ of_h, u16* __restrict__ of_l, float2* __restrict__ ml) {
    int bid = blockIdx.x;
    int b = bid & 7, r = bid >> 3;
    int sp = r >> 6, nt = r & 63;
    int w = threadIdx.x >> 6, lane = threadIdx.x & 63;
    int l15 = lane & 15, g16 = lane >> 4;
    int n = nt * 64 + w * 16 + l15;
    int t16 = nt * 4 + w;
    __shared__ u16 plds[4][16][40];

    f16x8 qf[4];
#pragma unroll
    for (int ks = 0; ks < 4; ++ks)
        qf[ks] = ldh8(&thf[((size_t)(b * 256 + t16) * 4 + ks) * 512 + (size_t)lane * 8]);

    f32x4 o[8];
#pragma unroll
    for (int ct = 0; ct < 8; ++ct)
#pragma unroll
        for (int rr = 0; rr < 4; ++rr) o[ct][rr] = 0.f;
    float mrun = -1e30f, lrun = 0.f;

    for (int it = 0; it < 16; ++it) {
        int itg = sp * 16 + it;
        f16x8 pa0[4], pa1[4], gv[8];
#pragma unroll
        for (int ks = 0; ks < 4; ++ks) {
            size_t p0 = ((size_t)((b * 32 + itg) * 2 + 0) * 4 + ks) * 512 + (size_t)lane * 8;
            size_t p1 = ((size_t)((b * 32 + itg) * 2 + 1) * 4 + ks) * 512 + (size_t)lane * 8;
            pa0[ks] = ldh8(&ppf[p0]);
            pa1[ks] = ldh8(&ppf[p1]);
        }
#pragma unroll
        for (int ct = 0; ct < 8; ++ct)
            gv[ct] = ldh8(&gpf[((size_t)(b * 32 + itg) * 8 + ct) * 512 + (size_t)lane * 8]);

        f32x4 s0 = {0.f, 0.f, 0.f, 0.f}, s1 = {0.f, 0.f, 0.f, 0.f};
#pragma unroll
        for (int ks = 0; ks < 4; ++ks) {
            s0 = MFMAH(pa0[ks], qf[ks], s0);
            s1 = MFMAH(pa1[ks], qf[ks], s1);
        }
        float pm = s0[0];
#pragma unroll
        for (int rr = 1; rr < 4; ++rr) pm = fmaxf(pm, s0[rr]);
#pragma unroll
        for (int rr = 0; rr < 4; ++rr) pm = fmaxf(pm, s1[rr]);
        pm = fmaxf(pm, __shfl_xor(pm, 16));
        pm = fmaxf(pm, __shfl_xor(pm, 32));
        float mnew = fmaxf(mrun, pm);
        float sc = __expf(mrun - mnew);
        float p[8];
        float ls = 0.f;
#pragma unroll
        for (int rr = 0; rr < 4; ++rr) { p[rr] = __expf(s0[rr] - mnew); ls += p[rr]; }
#pragma unroll
        for (int rr = 0; rr < 4; ++rr) { p[4 + rr] = __expf(s1[rr] - mnew); ls += p[4 + rr]; }
        ls += __shfl_xor(ls, 16);
        ls += __shfl_xor(ls, 32);
        lrun = lrun * sc + ls;
        mrun = mnew;
#pragma unroll
        for (int ct = 0; ct < 8; ++ct)
#pragma unroll
            for (int rr = 0; rr < 4; ++rr) o[ct][rr] *= sc;
        u16x4 pk0, pk1;
#pragma unroll
        for (int rr = 0; rr < 4; ++rr) { pk0[rr] = f2h(p[rr]); pk1[rr] = f2h(p[4 + rr]); }
        *reinterpret_cast<u16x4*>(&plds[w][l15][g16 * 4]) = pk0;
        *reinterpret_cast<u16x4*>(&plds[w][l15][16 + g16 * 4]) = pk1;
        asm volatile("s_waitcnt lgkmcnt(0)" ::: "memory");
        f16x8 pfr = ldh8(&plds[w][l15][g16 * 8]);
#pragma unroll
        for (int ct = 0; ct < 8; ++ct) o[ct] = MFMAH(gv[ct], pfr, o[ct]);
    }
    size_t obase = ((size_t)(b * 2 + sp) * N_ + n) * CI_;
#pragma unroll
    for (int ct = 0; ct < 8; ++ct) {
        u16x4 hh, ll;
#pragma unroll
        for (int rr = 0; rr < 4; ++rr) {
            u16 a, bb;
            split_bf(o[ct][rr], a, bb);
            hh[rr] = a;
            ll[rr] = bb;
        }
        *reinterpret_cast<u16x4*>(&of_h[obase + ct * 16 + g16 * 4]) = hh;
        *reinterpret_cast<u16x4*>(&of_l[obase + ct * 16 + g16 * 4]) = ll;
    }
    if (g16 == 0) ml[(size_t)(b * 2 + sp) * N_ + n] = make_float2(mrun, lrun);
}

// ---------------- combine 2 splits -> ytf fp16 fragment-linear ----------------
__global__ __launch_bounds__(256) void k_combine(
    const u16* __restrict__ of_h, const u16* __restrict__ of_l,
    const float2* __restrict__ ml, u16* __restrict__ ytf) {
    int idx = blockIdx.x * 256 + threadIdx.x;
    int b = idx >> 16, rem = idx & 65535, n = rem >> 4, c8 = rem & 15;
    float2 ml0 = ml[(size_t)(b * 2 + 0) * N_ + n];
    float2 ml1 = ml[(size_t)(b * 2 + 1) * N_ + n];
    float M = fmaxf(ml0.x, ml1.x);
    float w0 = __expf(ml0.x - M), w1 = __expf(ml1.x - M);
    float invL = 1.f / (w0 * ml0.y + w1 * ml1.y);
    float s0 = w0 * invL, s1 = w1 * invL;
    size_t b0 = ((size_t)(b * 2 + 0) * N_ + n) * CI_ + c8 * 8;
    size_t b1 = ((size_t)(b * 2 + 1) * N_ + n) * CI_ + c8 * 8;
    u16x8 h0 = *(const u16x8*)&of_h[b0], l0 = *(const u16x8*)&of_l[b0];
    u16x8 h1 = *(const u16x8*)&of_h[b1], l1 = *(const u16x8*)&of_l[b1];
    u16x8 y;
#pragma unroll
    for (int e = 0; e < 8; ++e) {
        float v = (bf2f(h0[e]) + bf2f(l0[e])) * s0 + (bf2f(h1[e]) + bf2f(l1[e])) * s1;
        y[e] = f2h(v);
    }
    size_t off = ((size_t)(b * 256 + (n >> 4)) * 4 + (c8 >> 2)) * 512 +
                 ((c8 & 3) * 16 + (n & 15)) * 8;
    *(u16x8*)&ytf[off] = y;
}

// ---------------- W conv GEMM (fp16, swapped operands, pure GEMM) ----------------
// D row = n (from ytf A-frag), col = ch (from wwf B-frag) -> lane's 4 regs are
// 4 consecutive n of one channel -> coalesced u16x4 stores.
__global__ __launch_bounds__(256) void k_wconv(
    const u16* __restrict__ wwf, const float* __restrict__ Wb,
    const u16* __restrict__ ytf, u16* __restrict__ z) {
    int bid = blockIdx.x;
    int b = bid >> 6, rem = bid & 63, ct2 = rem >> 5, nt = rem & 31;
    int w = threadIdx.x >> 6, lane = threadIdx.x & 63;
    int l15 = lane & 15, g16 = lane >> 4;
    int nbase = nt * 128 + (w >> 1) * 64;
    int cbase = ct2 * 128 + (w & 1) * 64;
    f32x4 acc[4][4];  // [i: n-16tile][j: ch-16tile]
#pragma unroll
    for (int i = 0; i < 4; ++i)
#pragma unroll
        for (int j = 0; j < 4; ++j)
#pragma unroll
            for (int r = 0; r < 4; ++r) acc[i][j][r] = 0.f;
#pragma unroll
    for (int ks = 0; ks < 4; ++ks) {
        f16x8 a[4], bb[4];
#pragma unroll
        for (int i = 0; i < 4; ++i)
            a[i] = ldh8(&ytf[((size_t)(b * 256 + (nbase >> 4) + i) * 4 + ks) * 512 +
                             (size_t)lane * 8]);
#pragma unroll
        for (int j = 0; j < 4; ++j)
            bb[j] = ldh8(&wwf[((size_t)((cbase >> 4) + j) * 4 + ks) * 512 + (size_t)lane * 8]);
#pragma unroll
        for (int i = 0; i < 4; ++i)
#pragma unroll
            for (int j = 0; j < 4; ++j) acc[i][j] = MFMAH(a[i], bb[j], acc[i][j]);
    }
#pragma unroll
    for (int j = 0; j < 4; ++j) {
        int ch = cbase + j * 16 + l15;
        float bias = Wb[ch];
        size_t rowbase = ((size_t)b * C_ + ch) * N_;
#pragma unroll
        for (int i = 0; i < 4; ++i) {
            u16x4 pk;
#pragma unroll
            for (int r = 0; r < 4; ++r) pk[r] = f2h(acc[i][j][r] + bias);
            *reinterpret_cast<u16x4*>(&z[rowbase + nbase + i * 16 + g16 * 4]) = pk;
        }
    }
}

// ---------------- BN stats + finalize (one block per channel, no atomics) ----------------
__global__ __launch_bounds__(256) void k_stats(
    const u16* __restrict__ z, const float* __restrict__ gamma,
    const float* __restrict__ beta, float* __restrict__ bnp) {
    int c = blockIdx.x;
    int tid = threadIdx.x;
    float s = 0.f, q = 0.f;
#pragma unroll
    for (int b = 0; b < B_; ++b) {
        size_t base = ((size_t)b * C_ + c) * N_ + tid * 16;
        u16x8 v0 = *(const u16x8*)&z[base];
        u16x8 v1 = *(const u16x8*)&z[base + 8];
#pragma unroll
        for (int e = 0; e < 8; ++e) {
            float v = h2f(v0[e]);
            s += v;
            q += v * v;
            float u = h2f(v1[e]);
            s += u;
            q += u * u;
        }
    }
#pragma unroll
    for (int off = 1; off <= 32; off <<= 1) {
        s += __shfl_xor(s, off);
        q += __shfl_xor(q, off);
    }
    __shared__ float ss[4], qq[4];
    int w = tid >> 6;
    if ((tid & 63) == 0) {
        ss[w] = s;
        qq[w] = q;
    }
    __syncthreads();
    if (tid == 0) {
        s = ss[0] + ss[1] + ss[2] + ss[3];
        q = qq[0] + qq[1] + qq[2] + qq[3];
        const float inv_n = 1.f / 32768.f;
        float mean = s * inv_n;
        float var = q * inv_n - mean * mean;
        float sc = gamma[c] * rsqrtf(var + 1e-5f);
        bnp[c] = sc;
        bnp[256 + c] = beta[c] - mean * sc;
    }
}

// ---------------- apply BN + residual ----------------
__global__ __launch_bounds__(256) void k_final(
    const float* __restrict__ x, const u16* __restrict__ z,
    const float* __restrict__ bnp, float* __restrict__ out) {
    int i4 = blockIdx.x * 256 + threadIdx.x;
    size_t flat = (size_t)i4 * 4;
    int c = (int)((flat >> 12) & 255);
    float sc = bnp[c], sh = bnp[256 + c];
    float4 xx = *(const float4*)&x[flat];
    u16x4 zz = *(const u16x4*)&z[flat];
    float4 oo;
    oo.x = xx.x + h2f(zz[0]) * sc + sh;
    oo.y = xx.y + h2f(zz[1]) * sc + sh;
    oo.z = xx.z + h2f(zz[2]) * sc + sh;
    oo.w = xx.w + h2f(zz[3]) * sc + sh;
    *(float4*)&out[flat] = oo;
}

extern "C" void kernel_launch(void* const* d_in, const int* in_sizes, int n_in,
                              void* d_out, int out_size, void* d_ws, size_t ws_size,
                              hipStream_t stream) {
    const float* x     = (const float*)d_in[0];
    const float* tw    = (const float*)d_in[1];
    const float* tb    = (const float*)d_in[2];
    const float* pw    = (const float*)d_in[3];
    const float* pb    = (const float*)d_in[4];
    const float* gw    = (const float*)d_in[5];
    const float* gb    = (const float*)d_in[6];
    const float* Ww    = (const float*)d_in[7];
    const float* Wb    = (const float*)d_in[8];
    const float* gamma = (const float*)d_in[9];
    const float* beta  = (const float*)d_in[10];
    float* out = (float*)d_out;

    char* p = (char*)d_ws;
    auto alloc = [&](size_t bytes) {
        char* r = p;
        p += (bytes + 255) & ~(size_t)255;
        return r;
    };
    u16* xbf_h = (u16*)alloc((size_t)B_ * N_ * C_ * 2);      // 16 MB, dead after k_proj
    u16* xbf_l = (u16*)alloc((size_t)B_ * N_ * C_ * 2);      // 16 MB
    u16* thf   = (u16*)alloc((size_t)B_ * N_ * CI_ * 2);     // 8 MB, dead after k_attn
    u16* pf    = (u16*)alloc((size_t)B_ * N_ * CI_ * 2);     // 8 MB, dead after pool_phi
    u16* gf    = (u16*)alloc((size_t)B_ * N_ * CI_ * 2);     // 8 MB, dead after pool_g
    u16* ppf   = (u16*)alloc((size_t)B_ * M_ * CI_ * 2);     // 2 MB
    u16* gpf   = (u16*)alloc((size_t)B_ * M_ * CI_ * 2);     // 2 MB
    u16* of_l  = (u16*)alloc((size_t)2 * B_ * N_ * CI_ * 2); // 16 MB
    float2* ml = (float2*)alloc((size_t)2 * B_ * N_ * 8);    // 512 KB
    u16* ytf   = (u16*)alloc((size_t)B_ * N_ * CI_ * 2);     // 8 MB
    u16* wcf_h = (u16*)alloc(384 * 256 * 2);
    u16* wcf_l = (u16*)alloc(384 * 256 * 2);
    u16* wwf   = (u16*)alloc(256 * 128 * 2);
    float* bcat = (float*)alloc(384 * 4);
    float* bnp  = (float*)alloc(512 * 4);
    // aliases (dead-region reuse):
    u16* of_h = pf;        // 16 MB over pf+gf (both dead before k_attn writes)
    u16* z    = xbf_h;     // z fp16 16 MiB == xbf_h exactly (dead before k_wconv)

    k_prep<<<514, 256, 0, stream>>>(tw, tb, pw, pb, gw, gb, Ww, wcf_h, wcf_l, bcat, wwf);
    k_tx<<<2048, 256, 0, stream>>>(x, xbf_h, xbf_l);
    k_proj<<<768, 256, 0, stream>>>(wcf_h, wcf_l, bcat, xbf_h, xbf_l, thf, pf, gf);
    k_pool_phi<<<512, 256, 0, stream>>>(pf, ppf);
    k_pool_g<<<256, 128, 0, stream>>>(gf, gpf);
    k_attn<<<1024, 256, 0, stream>>>(thf, ppf, gpf, of_h, of_l, ml);
    k_combine<<<2048, 256, 0, stream>>>(of_h, of_l, ml, ytf);
    k_wconv<<<512, 256, 0, stream>>>(wwf, Wb, ytf, z);
    k_stats<<<256, 256, 0, stream>>>(z, gamma, beta, bnp);
    k_final<<<8192, 256, 0, stream>>>(x, z, bnp, out);
}